// Round 5
// baseline (629.259 us; speedup 1.0000x reference)
//
#include <hip/hip_runtime.h>
#include <hip/hip_bf16.h>
#include <stdint.h>

// Problem constants
#define BATCH 4
#define SEQN  2048
#define DIMC  1024
#define NHEADS 16
#define DHEAD 64
#define BH_TOT 64          // BATCH*NHEADS
#define MROWS 8192         // BATCH*SEQN

typedef __attribute__((ext_vector_type(8))) short bf16x8;
typedef __attribute__((ext_vector_type(4))) float f32x4;

__device__ __forceinline__ unsigned short bf16_rtne(float f){
  union { float f; unsigned u; } v; v.f = f;
  unsigned u = v.u;
  return (unsigned short)((u + 0x7FFFu + ((u >> 16) & 1u)) >> 16);
}
__device__ __forceinline__ float bf16f(unsigned short h){
  union { unsigned u; float f; } v; v.u = ((unsigned)h) << 16;
  return v.f;
}
__device__ __forceinline__ unsigned cvt_pk_bf16(float lo, float hi){
  unsigned r;
  asm("v_cvt_pk_bf16_f32 %0, %1, %2" : "=v"(r) : "v"(lo), "v"(hi));
  return r;
}

__device__ __forceinline__ void async16(void* lds, const void* g){
  __builtin_amdgcn_global_load_lds((const __attribute__((address_space(1))) void*)g,
                                   (__attribute__((address_space(3))) void*)lds, 16, 0, 0);
}

// ---------------------------------------------------------------------------
// C1: split fp32 rows [nrows][Kc] -> bf16 [nrows][2*Kc] = [hi | lo]
// ---------------------------------------------------------------------------
__global__ __launch_bounds__(256) void split_rows_k(const float* __restrict__ X,
    unsigned short* __restrict__ O, int nrows, int Kc){
  int q4 = Kc >> 2;
  int total = nrows * q4;
  int idx = blockIdx.x*256 + threadIdx.x;
  if (idx >= total) return;
  int row = idx / q4, c = idx - row*q4;
  const float4 v = *(const float4*)(X + ((size_t)row*Kc + c*4));
  float fv[4] = {v.x, v.y, v.z, v.w};
  unsigned short hi[4], lo[4];
#pragma unroll
  for (int j=0;j<4;j++){ hi[j] = bf16_rtne(fv[j]); lo[j] = bf16_rtne(fv[j] - bf16f(hi[j])); }
  size_t ob = (size_t)row*(2*Kc) + c*4;
  ushort4 h; h.x=hi[0]; h.y=hi[1]; h.z=hi[2]; h.w=hi[3];
  ushort4 l2; l2.x=lo[0]; l2.y=lo[1]; l2.z=lo[2]; l2.w=lo[3];
  *(ushort4*)(O + ob) = h;
  *(ushort4*)(O + ob + Kc) = l2;
}

// ---------------------------------------------------------------------------
// C2: transpose + split: W [K][Nc] f32 -> Wt [Nc][2K] bf16 (hi | lo)
// ---------------------------------------------------------------------------
__global__ __launch_bounds__(256) void transpose_split_k(const float* __restrict__ W,
    unsigned short* __restrict__ Wt, int K, int Nc){
  __shared__ float tile[32][33];
  int tx = threadIdx.x & 31, ty = threadIdx.x >> 5;   // 32 x 8
  int n0 = blockIdx.x*32, k0 = blockIdx.y*32;
#pragma unroll
  for (int i=0;i<4;i++){
    int k = k0 + ty + i*8;
    tile[ty + i*8][tx] = W[(size_t)k*Nc + n0 + tx];
  }
  __syncthreads();
#pragma unroll
  for (int i=0;i<4;i++){
    int n = n0 + ty + i*8;
    float f = tile[tx][ty + i*8];
    unsigned short hi = bf16_rtne(f);
    unsigned short lo = bf16_rtne(f - bf16f(hi));
    Wt[(size_t)n*(2*K) + k0 + tx] = hi;
    Wt[(size_t)n*(2*K) + K + k0 + tx] = lo;
  }
}

// ---------------------------------------------------------------------------
// Split-bf16 GEMM, counted-vmcnt 2-phase pipeline.
//   A [M][2K] = [Ah|Al], Bt [Nc][2K] = [Bh|Bl]; virtual K' = 3K.
// 128x128 tile, BK=64 split into 2 kk-phases (16 MFMA each). Per phase:
//   vmcnt(4) [counted: waits only the slab needed NOW, 4 loads stay in
//   flight]; raw s_barrier (NOT __syncthreads - that drains vmcnt(0));
//   8 ds_read_b128 from identity-mapped 1024B blocks (conflict-free);
//   stage next tile's matching kk-slab (4 global_load_lds);
//   setprio(1); 16 MFMA; setprio(0).
// LDS 64KB -> 2 blocks/CU; slab staged a full K-tile before its use.
// ---------------------------------------------------------------------------
__global__ __launch_bounds__(256, 2) void gemm_split_k(
    const unsigned short* __restrict__ A, const unsigned short* __restrict__ Bt,
    float* __restrict__ C, const float* __restrict__ bias, int M, int Nc, int K)
{
  // [dbuf][kk][8 blocks x 512 ushort]; block F holds rows F*16..+15 of the
  // 128-row panel, chunk c = lane>>4 (8 bf16 along k); slot l = identity.
  __shared__ unsigned short a_lds[2][2][4096];
  __shared__ unsigned short b_lds[2][2][4096];
  const int t = threadIdx.x, w = t>>6, l = t&63, lg = l>>4, ll = l&15;
  const int wr = w>>1, wc = w&1;
  const int nbm = M>>7;
  const int nwg = nbm*(Nc>>7);
  const int orig = blockIdx.x;
  const int id = ((orig&7)*(nwg>>3)) + (orig>>3);     // XCD swizzle (nwg%8==0)
  const int m0 = (id & (nbm-1))<<7, n0 = (id/nbm)<<7;
  const int ldk = 2*K;
  const int nkt = (3*K)>>6;                            // 48 K-tiles of 64
  f32x4 acc[4][4];
#pragma unroll
  for (int m=0;m<4;m++)
#pragma unroll
    for (int n=0;n<4;n++) acc[m][n] = (f32x4){0.f,0.f,0.f,0.f};

  // stage the kk-slab (A 128x32 + B 128x32) of K-tile kt into dbuf d.
  // 4 VMEM instructions per call. LDS dest j*16B, j=i*256+t -> block i*4+w,
  // slot l; global source chosen so slot l = (row F*16+ll, chunk lg).
  auto stage = [&](int d, int kk, int kt){
    const int kp = kt<<6;
    const int ac = (kp <   K) ? kp : kp -   K;   // A: Ah,Ah,Al
    const int bc = (kp < 2*K) ? kp : kp - 2*K;   // B: Bh,Bl,Bh
#pragma unroll
    for (int i=0;i<2;i++){
      int F = i*4 + w;
      async16(&a_lds[d][kk][(i*256+t)*8],
              A + (size_t)(m0 + F*16 + ll)*ldk + ac + kk*32 + lg*8);
    }
#pragma unroll
    for (int i=0;i<2;i++){
      int F = i*4 + w;
      async16(&b_lds[d][kk][(i*256+t)*8],
              Bt + (size_t)(n0 + F*16 + ll)*ldk + bc + kk*32 + lg*8);
    }
  };

  stage(0, 0, 0);
  stage(0, 1, 0);

  for (int kt=0; kt<nkt-1; ++kt){
    const int d = kt&1;
#pragma unroll
    for (int kk=0; kk<2; ++kk){
      asm volatile("s_waitcnt vmcnt(4)" ::: "memory");
      __builtin_amdgcn_s_barrier();
      __builtin_amdgcn_sched_barrier(0);
      bf16x8 af[4], bfr[4];
#pragma unroll
      for (int fm=0;fm<4;fm++)
        af[fm] = *(const bf16x8*)&a_lds[d][kk][(wr*4+fm)*512 + l*8];
#pragma unroll
      for (int fn=0;fn<4;fn++)
        bfr[fn] = *(const bf16x8*)&b_lds[d][kk][(wc*4+fn)*512 + l*8];
      stage(d^1, kk, kt+1);
      __builtin_amdgcn_s_setprio(1);
#pragma unroll
      for (int fm=0;fm<4;fm++)
#pragma unroll
        for (int fn=0;fn<4;fn++)
          acc[fm][fn] = __builtin_amdgcn_mfma_f32_16x16x32_bf16(af[fm], bfr[fn], acc[fm][fn], 0,0,0);
      __builtin_amdgcn_s_setprio(0);
    }
  }
  // last K-tile (no staging)
  {
    const int d = (nkt-1)&1;
#pragma unroll
    for (int kk=0; kk<2; ++kk){
      if (kk==0) asm volatile("s_waitcnt vmcnt(4)" ::: "memory");
      else       asm volatile("s_waitcnt vmcnt(0)" ::: "memory");
      __builtin_amdgcn_s_barrier();
      __builtin_amdgcn_sched_barrier(0);
      bf16x8 af[4], bfr[4];
#pragma unroll
      for (int fm=0;fm<4;fm++)
        af[fm] = *(const bf16x8*)&a_lds[d][kk][(wr*4+fm)*512 + l*8];
#pragma unroll
      for (int fn=0;fn<4;fn++)
        bfr[fn] = *(const bf16x8*)&b_lds[d][kk][(wc*4+fn)*512 + l*8];
      __builtin_amdgcn_s_setprio(1);
#pragma unroll
      for (int fm=0;fm<4;fm++)
#pragma unroll
        for (int fn=0;fn<4;fn++)
          acc[fm][fn] = __builtin_amdgcn_mfma_f32_16x16x32_bf16(af[fm], bfr[fn], acc[fm][fn], 0,0,0);
      __builtin_amdgcn_s_setprio(0);
    }
  }

#pragma unroll
  for (int fm=0;fm<4;fm++)
#pragma unroll
    for (int fn=0;fn<4;fn++){
      int col = n0 + wc*64 + fn*16 + ll;
      float bv = bias ? bias[col] : 0.f;
#pragma unroll
      for (int r=0;r<4;r++){
        int row = m0 + wr*64 + fm*16 + lg*4 + r;
        C[(size_t)row*Nc + col] = acc[fm][fn][r] + bv;
      }
    }
}

// ---------------------------------------------------------------------------
// C4a: qkv f32 [B*N][3072] -> q_hl [BH][N][128] (hi|lo of SCALED q),
//                            k_h  [BH][N][64]  (hi only)
// Q prescaled by 0.125*log2(e) so attention uses exp2 directly.
// ---------------------------------------------------------------------------
#define QSCALE 0.18033688f
__global__ __launch_bounds__(256) void split_qk_k(const float* __restrict__ qkv,
    unsigned short* __restrict__ Qo, unsigned short* __restrict__ Ko){
  int idx = blockIdx.x*256 + threadIdx.x;      // BH*N*16 threads exactly
  int d4 = idx & 15, n = (idx>>4) & (SEQN-1), bh = idx >> 15;
  int b = bh>>4, h = bh&15;
  size_t base = ((size_t)(b*SEQN + n))*3072 + h*64 + d4*4;
  float4 q = *(const float4*)(qkv + base);
  float4 k = *(const float4*)(qkv + base + 1024);
  float fq[4] = {q.x*QSCALE, q.y*QSCALE, q.z*QSCALE, q.w*QSCALE};
  float fk[4] = {k.x, k.y, k.z, k.w};
  unsigned short qh[4], ql[4], kh[4];
#pragma unroll
  for (int j=0;j<4;j++){
    qh[j] = bf16_rtne(fq[j]); ql[j] = bf16_rtne(fq[j] - bf16f(qh[j]));
    kh[j] = bf16_rtne(fk[j]);
  }
  size_t obq = ((size_t)bh*SEQN + n)*128 + d4*4;
  size_t obk = ((size_t)bh*SEQN + n)*64 + d4*4;
  ushort4 u;
  u.x=qh[0];u.y=qh[1];u.z=qh[2];u.w=qh[3]; *(ushort4*)(Qo+obq) = u;
  u.x=ql[0];u.y=ql[1];u.z=ql[2];u.w=ql[3]; *(ushort4*)(Qo+obq+64) = u;
  u.x=kh[0];u.y=kh[1];u.z=kh[2];u.w=kh[3]; *(ushort4*)(Ko+obk) = u;
}

// ---------------------------------------------------------------------------
// C4b: V transpose: qkv -> Vt bf16 [BH][DHEAD][SEQN]
// ---------------------------------------------------------------------------
__global__ __launch_bounds__(256) void build_vt_k(const float* __restrict__ qkv,
    unsigned short* __restrict__ Vt){
  __shared__ float tile[64][65];
  const int mt = blockIdx.x, bh = blockIdx.y;
  const int b = bh>>4, h = bh&15;
  const int t = threadIdx.x;
  const int r = t>>2, seg = t&3;
  size_t src = ((size_t)(b*SEQN + mt*64 + r))*3072 + 2048 + h*64 + seg*16;
#pragma unroll
  for (int j=0;j<4;j++){
    float4 v = *(const float4*)(qkv + src + j*4);
    tile[r][seg*16 + j*4 + 0] = v.x;
    tile[r][seg*16 + j*4 + 1] = v.y;
    tile[r][seg*16 + j*4 + 2] = v.z;
    tile[r][seg*16 + j*4 + 3] = v.w;
  }
  __syncthreads();
  const int d = r, ms = seg;
  unsigned short o16[16];
#pragma unroll
  for (int j=0;j<16;j++) o16[j] = bf16_rtne(tile[ms*16 + j][d]);
  size_t dst = ((size_t)(bh*64 + d))*SEQN + mt*64 + ms*16;
  uint4 u0, u1;
  unsigned* pu = (unsigned*)&u0;
  unsigned* pv = (unsigned*)&u1;
#pragma unroll
  for (int j=0;j<4;j++){
    pu[j] = (unsigned)o16[2*j]   | ((unsigned)o16[2*j+1]<<16);
    pv[j] = (unsigned)o16[8+2*j] | ((unsigned)o16[9+2*j]<<16);
  }
  *(uint4*)(Vt + dst) = u0;
  *(uint4*)(Vt + dst + 8) = u1;
}

// ---------------------------------------------------------------------------
// K2: flash attention, swapped QK^T. S = (Qh+Ql)·Kh.
// Epilogue FUSED with the hi/lo split: writes att_hl [row][2048] directly.
// ---------------------------------------------------------------------------
__global__ __launch_bounds__(256, 4) void attn_k(const unsigned short* __restrict__ Q,
    const unsigned short* __restrict__ Kh, const unsigned short* __restrict__ Vt,
    unsigned short* __restrict__ att_hl)
{
  __shared__ unsigned short k_lds[2][4096];   // [64][64] x2
  __shared__ unsigned short v_lds[2][4096];   // [64][64] x2 (rows = d, cols = kv)
  __shared__ unsigned p_lds[4][512];          // per-wave [16 q][32 u32]
  const int orig = blockIdx.y*gridDim.x + blockIdx.x;   // grid (32, 64)
  const int id = ((orig & 7) << 8) + (orig >> 3);       // XCD swizzle, 2048 wgs
  const int qt = id & 31, bh = id >> 5;
  const int b = bh>>4, h = bh&15;
  const int t = threadIdx.x, w = t>>6, l = t&63, lg = l>>4, ll = l&15;
  const size_t kvbase = (size_t)bh*SEQN;

  // Q fragments (B-operand): chunks 0,1 = Qh, 2,3 = Ql
  bf16x8 qf[4];
  {
    size_t qrow = (kvbase + qt*64 + w*16 + ll) * 128;
#pragma unroll
    for (int i=0;i<4;i++)
      qf[i] = *(const bf16x8*)(Q + qrow + i*32 + lg*8);
  }
  f32x4 o[4];
#pragma unroll
  for (int d=0; d<4; d++) o[d] = (f32x4){0.f,0.f,0.f,0.f};
  float lsum = 0.f;

  auto stage = [&](int buf, int kv){
    int m0 = kv*64;
#pragma unroll
    for (int i=0;i<2;i++){   // K tile: [64][64] ush, 512 x 16B slots
      int s = t + i*256; int row = s>>3; int sl = s&7; int sl2 = sl ^ (row&7);
      async16(&k_lds[buf][s*8], Kh + (kvbase + m0 + row)*64 + sl2*8);
    }
#pragma unroll
    for (int i=0;i<2;i++){   // V tile: [64][64] ush, 512 x 16B slots
      int s = t + i*256; int row = s>>3; int sl = s&7; int sl2 = sl ^ (row&7);
      async16(&v_lds[buf][s*8], Vt + ((size_t)bh*64 + row)*SEQN + m0 + sl2*8);
    }
  };

  stage(0, 0);
  __syncthreads();
  const int NKV = SEQN/64;
  for (int kv=0; kv<NKV; ++kv){
    int cur = kv&1;
    if (kv+1 < NKV) stage(cur^1, kv+1);
    // scores (swapped): S^T frag = mfma(K, Q); lane: q=ll, kv=nt*16+lg*4+r
#pragma unroll
    for (int nt=0; nt<4; ++nt){
      int row = nt*16 + ll;
      bf16x8 kf0 = *(const bf16x8*)&k_lds[cur][row*64 + (((0*4+lg) ^ (row&7))*8)];
      bf16x8 kf1 = *(const bf16x8*)&k_lds[cur][row*64 + (((1*4+lg) ^ (row&7))*8)];
      f32x4 a = (f32x4){0.f,0.f,0.f,0.f};
      __builtin_amdgcn_s_setprio(1);
      a = __builtin_amdgcn_mfma_f32_16x16x32_bf16(kf0, qf[0], a, 0,0,0);
      a = __builtin_amdgcn_mfma_f32_16x16x32_bf16(kf1, qf[1], a, 0,0,0);
      a = __builtin_amdgcn_mfma_f32_16x16x32_bf16(kf0, qf[2], a, 0,0,0);
      a = __builtin_amdgcn_mfma_f32_16x16x32_bf16(kf1, qf[3], a, 0,0,0);
      __builtin_amdgcn_s_setprio(0);
      float e0 = exp2f(a[0]), e1 = exp2f(a[1]), e2 = exp2f(a[2]), e3 = exp2f(a[3]);
      lsum += (e0 + e1) + (e2 + e3);
      unsigned pk0 = cvt_pk_bf16(e0, e1);
      unsigned pk1 = cvt_pk_bf16(e2, e3);
      // u32 col c0 = nt*8+lg*2 (even): chunk = c0>>2, pos = c0&3
      int c0 = nt*8 + lg*2;
      int addr = ll*32 + (((c0>>2) ^ (ll&7))<<2) + (c0&3);
      *(uint2*)&p_lds[w][addr] = make_uint2(pk0, pk1);
    }
    // PV: o += P @ V
#pragma unroll
    for (int ks=0; ks<2; ++ks){
      int chunk = ks*4 + lg;
      bf16x8 pf = *(const bf16x8*)&p_lds[w][ll*32 + ((chunk ^ (ll&7))<<2)];
      __builtin_amdgcn_s_setprio(1);
#pragma unroll
      for (int dt=0; dt<4; ++dt){
        int row = dt*16 + ll;
        bf16x8 vf = *(const bf16x8*)&v_lds[cur][row*64 + (((ks*4+lg) ^ (row&7))*8)];
        o[dt] = __builtin_amdgcn_mfma_f32_16x16x32_bf16(pf, vf, o[dt], 0,0,0);
      }
      __builtin_amdgcn_s_setprio(0);
    }
    __syncthreads();
  }
  // softmax denominator: lane ll holds partial for q=ll; reduce across lg groups
  float tot = lsum;
  tot += __shfl_xor(tot, 16);
  tot += __shfl_xor(tot, 32);
  float inv = 1.0f / tot;
  // output: o[dt][r] is O[q=lg*4+r][d=dt*16+ll]; write hi|lo split directly
#pragma unroll
  for (int r=0;r<4;r++){
    float rl = __shfl(inv, lg*4 + r);
    int qrow = qt*64 + w*16 + lg*4 + r;
    size_t ob = ((size_t)(b*SEQN + qrow))*2048 + h*64;
#pragma unroll
    for (int dt=0; dt<4; ++dt){
      float f = o[dt][r] * rl;
      unsigned short hi = bf16_rtne(f);
      unsigned short lo = bf16_rtne(f - bf16f(hi));
      att_hl[ob + dt*16 + ll] = hi;
      att_hl[ob + 1024 + dt*16 + ll] = lo;
    }
  }
}

// ---------------------------------------------------------------------------
extern "C" void kernel_launch(void* const* d_in, const int* in_sizes, int n_in,
                              void* d_out, int out_size, void* d_ws, size_t ws_size,
                              hipStream_t stream){
  const float* x    = (const float*)d_in[0];
  const float* Wqkv = (const float*)d_in[1];
  const float* Wout = (const float*)d_in[2];
  const float* bout = (const float*)d_in[3];
  float* out = (float*)d_out;

  char* ws = (char*)d_ws;
  size_t off = 0;
  auto walloc = [&](size_t bytes) -> void* {
    void* p = ws + off; off += (bytes + 255) & ~(size_t)255; return p;
  };
  unsigned short* x_hl   = (unsigned short*)walloc((size_t)MROWS*2048*2);      // 33.5 MB
  unsigned short* wqkv_t = (unsigned short*)walloc((size_t)3072*2048*2);       // 12.6 MB
  float*          qkv    = (float*)walloc((size_t)MROWS*3072*4);               // 100.7 MB
  unsigned short* q_hl   = (unsigned short*)walloc((size_t)BH_TOT*SEQN*128*2); // 33.5 MB
  unsigned short* k_h    = (unsigned short*)walloc((size_t)BH_TOT*SEQN*64*2);  // 16.8 MB
  unsigned short* vt     = (unsigned short*)walloc((size_t)BH_TOT*64*SEQN*2);  // 16.8 MB
  unsigned short* wout_t = (unsigned short*)walloc((size_t)1024*2048*2);       // 4.2 MB
  unsigned short* att_hl = x_hl;    // alias: x_hl dead after QKV GEMM

  // 1) hi/lo split of x
  split_rows_k<<<8192, 256, 0, stream>>>(x, x_hl, MROWS, DIMC);
  // 2) transpose+split weights
  transpose_split_k<<<dim3(3072/32, 1024/32), 256, 0, stream>>>(Wqkv, wqkv_t, 1024, 3072);
  transpose_split_k<<<dim3(1024/32, 1024/32), 256, 0, stream>>>(Wout, wout_t, 1024, 1024);
  // 3) QKV projection (split GEMM, K'=3072), grid 64x24=1536 blocks (1-D)
  gemm_split_k<<<1536, 256, 0, stream>>>(x_hl, wqkv_t, qkv, nullptr, MROWS, 3072, 1024);
  // 4) extract q (scaled hi/lo), k (hi) and V^T
  split_qk_k<<<(BH_TOT*SEQN*16)/256, 256, 0, stream>>>(qkv, q_hl, k_h);
  build_vt_k<<<dim3(SEQN/64, BH_TOT), 256, 0, stream>>>(qkv, vt);
  // 5) attention (epilogue writes hi/lo split directly)
  attn_k<<<dim3(SEQN/64, BH_TOT), 256, 0, stream>>>(q_hl, k_h, vt, att_hl);
  // 6) output projection + bias, grid 64x8=512 blocks (1-D)
  gemm_split_k<<<512, 256, 0, stream>>>(att_hl, wout_t, out, bout, MROWS, 1024, 1024);
}

// Round 6
// 559.488 us; speedup vs baseline: 1.1247x; 1.1247x over previous
//
#include <hip/hip_runtime.h>
#include <hip/hip_bf16.h>
#include <stdint.h>

// Problem constants
#define BATCH 4
#define SEQN  2048
#define DIMC  1024
#define NHEADS 16
#define DHEAD 64
#define BH_TOT 64          // BATCH*NHEADS
#define MROWS 8192         // BATCH*SEQN

typedef __attribute__((ext_vector_type(8))) short bf16x8;
typedef __attribute__((ext_vector_type(4))) float f32x4;

__device__ __forceinline__ unsigned short bf16_rtne(float f){
  union { float f; unsigned u; } v; v.f = f;
  unsigned u = v.u;
  return (unsigned short)((u + 0x7FFFu + ((u >> 16) & 1u)) >> 16);
}
__device__ __forceinline__ float bf16f(unsigned short h){
  union { unsigned u; float f; } v; v.u = ((unsigned)h) << 16;
  return v.f;
}
__device__ __forceinline__ unsigned cvt_pk_bf16(float lo, float hi){
  unsigned r;
  asm("v_cvt_pk_bf16_f32 %0, %1, %2" : "=v"(r) : "v"(lo), "v"(hi));
  return r;
}

__device__ __forceinline__ void async16(void* lds, const void* g){
  __builtin_amdgcn_global_load_lds((const __attribute__((address_space(1))) void*)g,
                                   (__attribute__((address_space(3))) void*)lds, 16, 0, 0);
}

// ---------------------------------------------------------------------------
// C1: split fp32 rows [nrows][Kc] -> bf16 [nrows][2*Kc] = [hi | lo]
// ---------------------------------------------------------------------------
__global__ __launch_bounds__(256) void split_rows_k(const float* __restrict__ X,
    unsigned short* __restrict__ O, int nrows, int Kc){
  int q4 = Kc >> 2;
  int total = nrows * q4;
  int idx = blockIdx.x*256 + threadIdx.x;
  if (idx >= total) return;
  int row = idx / q4, c = idx - row*q4;
  const float4 v = *(const float4*)(X + ((size_t)row*Kc + c*4));
  float fv[4] = {v.x, v.y, v.z, v.w};
  unsigned short hi[4], lo[4];
#pragma unroll
  for (int j=0;j<4;j++){ hi[j] = bf16_rtne(fv[j]); lo[j] = bf16_rtne(fv[j] - bf16f(hi[j])); }
  size_t ob = (size_t)row*(2*Kc) + c*4;
  ushort4 h; h.x=hi[0]; h.y=hi[1]; h.z=hi[2]; h.w=hi[3];
  ushort4 l2; l2.x=lo[0]; l2.y=lo[1]; l2.z=lo[2]; l2.w=lo[3];
  *(ushort4*)(O + ob) = h;
  *(ushort4*)(O + ob + Kc) = l2;
}

// ---------------------------------------------------------------------------
// C2: transpose + split: W [K][Nc] f32 -> Wt [Nc][2K] bf16 (hi | lo)
// ---------------------------------------------------------------------------
__global__ __launch_bounds__(256) void transpose_split_k(const float* __restrict__ W,
    unsigned short* __restrict__ Wt, int K, int Nc){
  __shared__ float tile[32][33];
  int tx = threadIdx.x & 31, ty = threadIdx.x >> 5;   // 32 x 8
  int n0 = blockIdx.x*32, k0 = blockIdx.y*32;
#pragma unroll
  for (int i=0;i<4;i++){
    int k = k0 + ty + i*8;
    tile[ty + i*8][tx] = W[(size_t)k*Nc + n0 + tx];
  }
  __syncthreads();
#pragma unroll
  for (int i=0;i<4;i++){
    int n = n0 + ty + i*8;
    float f = tile[tx][ty + i*8];
    unsigned short hi = bf16_rtne(f);
    unsigned short lo = bf16_rtne(f - bf16f(hi));
    Wt[(size_t)n*(2*K) + k0 + tx] = hi;
    Wt[(size_t)n*(2*K) + K + k0 + tx] = lo;
  }
}

// ---------------------------------------------------------------------------
// Split-bf16 GEMM, deep-prefetch pipeline.
//   A [M][2K] = [Ah|Al], Bt [Nc][2K] = [Bh|Bl]; virtual K' = 3K.
// Tile 256(M) x 128(N), BK=32. 512 threads = 8 waves as 4(M) x 2(N);
// per-wave C = 64x64 = 4x4 16x16 frags. LDS: 3 buffers (A 16KB + B 8KB each)
// = 72 KB -> 2 blocks/CU. Stage tile j+2 (into buf (j+2)%3) while computing
// tile j: writes never touch the buffer being read, so ONE raw s_barrier per
// K-tile and a counted vmcnt(3) (never 0 in steady state) are the only syncs.
// Loads get ~2 K-tiles of slack to land. No sched_barrier (m141), no
// __syncthreads (vmcnt(0) drain). LDS blocks: 1KB per (16-row frag), lane l
// holds 16B at l*16 -> identity ds_read_b128, 0 bank conflicts (verified r5);
// global source carries the permutation (rule #21).
// ---------------------------------------------------------------------------
__global__ __launch_bounds__(512, 4) void gemm_split_k(
    const unsigned short* __restrict__ A, const unsigned short* __restrict__ Bt,
    float* __restrict__ C, const float* __restrict__ bias, int M, int Nc, int K)
{
  __shared__ unsigned short a_lds[3*8192];   // 3 x [16 blocks x 512 ush] (256 rows x 32 cols)
  __shared__ unsigned short b_lds[3*4096];   // 3 x [ 8 blocks x 512 ush] (128 rows x 32 cols)
  const int t = threadIdx.x, wid = t>>6, l = t&63, lg = l>>4, ll = l&15;
  const int wm = wid>>1, wn = wid&1;
  const int nbm = M>>8;
  const int nwg = nbm*(Nc>>7);
  const int orig = blockIdx.x;
  const int id = ((orig&7)*(nwg>>3)) + (orig>>3);   // XCD swizzle (nwg%8==0)
  const int m0 = (id % nbm)<<8, n0 = (id / nbm)<<7;
  const int ldk = 2*K;
  const int nkt = (3*K)>>5;                          // virtual K' = 3K, BK=32
  f32x4 acc[4][4];
#pragma unroll
  for (int i=0;i<4;i++)
#pragma unroll
    for (int j=0;j<4;j++) acc[i][j] = (f32x4){0.f,0.f,0.f,0.f};

  // Stage K-tile kt2 into buffer wb. 3 loads/thread (A:2, B:1), 16B each.
  // Block b is wave-uniform; lane l lands at block*1KB + l*16B (identity).
  auto stageA = [&](int wb, int kt2){
    const int kp = kt2<<5;
    const int ac = (kp < K) ? kp : kp - K;       // A: Ah,Ah,Al
#pragma unroll
    for (int i=0;i<2;i++){
      int b = i*8 + wid;
      async16(&a_lds[wb*8192 + b*512 + l*8],
              A + (size_t)(m0 + b*16 + ll)*ldk + ac + lg*8);
    }
  };
  auto stageB = [&](int wb, int kt2){
    const int kp = kt2<<5;
    const int bc = (kp < 2*K) ? kp : kp - 2*K;   // B: Bh,Bl,Bh
    async16(&b_lds[wb*4096 + wid*512 + l*8],
            Bt + (size_t)(n0 + wid*16 + ll)*ldk + bc + lg*8);
  };

  stageA(0, 0); stageB(0, 0);
  stageA(1, 1); stageB(1, 1);

  for (int kt=0; kt<nkt; ++kt){
    // counted wait: tile kt's 3 loads are the oldest; tile kt+1's 3 may fly.
    if (kt < nkt-1) asm volatile("s_waitcnt vmcnt(3)\n\ts_barrier" ::: "memory");
    else            asm volatile("s_waitcnt vmcnt(0)\n\ts_barrier" ::: "memory");
    const int rb = kt % 3;
    const unsigned short* ab = &a_lds[rb*8192];
    const unsigned short* bb = &b_lds[rb*4096];
    bf16x8 af[4], bf[4];
#pragma unroll
    for (int i=0;i<4;i++) af[i] = *(const bf16x8*)&ab[(wm*4+i)*512 + l*8];
#pragma unroll
    for (int j=0;j<4;j++) bf[j] = *(const bf16x8*)&bb[(wn*4+j)*512 + l*8];
    if (kt+2 < nkt){
      const int wb = (kt+2) % 3;
      stageA(wb, kt+2); stageB(wb, kt+2);
    }
    __builtin_amdgcn_s_setprio(1);
#pragma unroll
    for (int i=0;i<4;i++)
#pragma unroll
      for (int j=0;j<4;j++)
        acc[i][j] = __builtin_amdgcn_mfma_f32_16x16x32_bf16(af[i], bf[j], acc[i][j], 0,0,0);
    __builtin_amdgcn_s_setprio(0);
  }

#pragma unroll
  for (int i=0;i<4;i++)
#pragma unroll
    for (int j=0;j<4;j++){
      int col = n0 + wn*64 + j*16 + ll;
      float bv = bias ? bias[col] : 0.f;
#pragma unroll
      for (int r=0;r<4;r++){
        int row = m0 + wm*64 + i*16 + lg*4 + r;
        C[(size_t)row*Nc + col] = acc[i][j][r] + bv;
      }
    }
}

// ---------------------------------------------------------------------------
// C4a: qkv f32 [B*N][3072] -> q_hl [BH][N][128] (hi|lo of SCALED q),
//                            k_h  [BH][N][64]  (hi only)
// Q prescaled by 0.125*log2(e) so attention uses exp2 directly.
// ---------------------------------------------------------------------------
#define QSCALE 0.18033688f
__global__ __launch_bounds__(256) void split_qk_k(const float* __restrict__ qkv,
    unsigned short* __restrict__ Qo, unsigned short* __restrict__ Ko){
  int idx = blockIdx.x*256 + threadIdx.x;      // BH*N*16 threads exactly
  int d4 = idx & 15, n = (idx>>4) & (SEQN-1), bh = idx >> 15;
  int b = bh>>4, h = bh&15;
  size_t base = ((size_t)(b*SEQN + n))*3072 + h*64 + d4*4;
  float4 q = *(const float4*)(qkv + base);
  float4 k = *(const float4*)(qkv + base + 1024);
  float fq[4] = {q.x*QSCALE, q.y*QSCALE, q.z*QSCALE, q.w*QSCALE};
  float fk[4] = {k.x, k.y, k.z, k.w};
  unsigned short qh[4], ql[4], kh[4];
#pragma unroll
  for (int j=0;j<4;j++){
    qh[j] = bf16_rtne(fq[j]); ql[j] = bf16_rtne(fq[j] - bf16f(qh[j]));
    kh[j] = bf16_rtne(fk[j]);
  }
  size_t obq = ((size_t)bh*SEQN + n)*128 + d4*4;
  size_t obk = ((size_t)bh*SEQN + n)*64 + d4*4;
  ushort4 u;
  u.x=qh[0];u.y=qh[1];u.z=qh[2];u.w=qh[3]; *(ushort4*)(Qo+obq) = u;
  u.x=ql[0];u.y=ql[1];u.z=ql[2];u.w=ql[3]; *(ushort4*)(Qo+obq+64) = u;
  u.x=kh[0];u.y=kh[1];u.z=kh[2];u.w=kh[3]; *(ushort4*)(Ko+obk) = u;
}

// ---------------------------------------------------------------------------
// C4b: V transpose: qkv -> Vt bf16 [BH][DHEAD][SEQN]
// ---------------------------------------------------------------------------
__global__ __launch_bounds__(256) void build_vt_k(const float* __restrict__ qkv,
    unsigned short* __restrict__ Vt){
  __shared__ float tile[64][65];
  const int mt = blockIdx.x, bh = blockIdx.y;
  const int b = bh>>4, h = bh&15;
  const int t = threadIdx.x;
  const int r = t>>2, seg = t&3;
  size_t src = ((size_t)(b*SEQN + mt*64 + r))*3072 + 2048 + h*64 + seg*16;
#pragma unroll
  for (int j=0;j<4;j++){
    float4 v = *(const float4*)(qkv + src + j*4);
    tile[r][seg*16 + j*4 + 0] = v.x;
    tile[r][seg*16 + j*4 + 1] = v.y;
    tile[r][seg*16 + j*4 + 2] = v.z;
    tile[r][seg*16 + j*4 + 3] = v.w;
  }
  __syncthreads();
  const int d = r, ms = seg;
  unsigned short o16[16];
#pragma unroll
  for (int j=0;j<16;j++) o16[j] = bf16_rtne(tile[ms*16 + j][d]);
  size_t dst = ((size_t)(bh*64 + d))*SEQN + mt*64 + ms*16;
  uint4 u0, u1;
  unsigned* pu = (unsigned*)&u0;
  unsigned* pv = (unsigned*)&u1;
#pragma unroll
  for (int j=0;j<4;j++){
    pu[j] = (unsigned)o16[2*j]   | ((unsigned)o16[2*j+1]<<16);
    pv[j] = (unsigned)o16[8+2*j] | ((unsigned)o16[9+2*j]<<16);
  }
  *(uint4*)(Vt + dst) = u0;
  *(uint4*)(Vt + dst + 8) = u1;
}

// ---------------------------------------------------------------------------
// K2: flash attention, swapped QK^T. S = (Qh+Ql)·Kh.
// Epilogue FUSED with the hi/lo split: writes att_hl [row][2048] directly.
// ---------------------------------------------------------------------------
__global__ __launch_bounds__(256, 4) void attn_k(const unsigned short* __restrict__ Q,
    const unsigned short* __restrict__ Kh, const unsigned short* __restrict__ Vt,
    unsigned short* __restrict__ att_hl)
{
  __shared__ unsigned short k_lds[2][4096];   // [64][64] x2
  __shared__ unsigned short v_lds[2][4096];   // [64][64] x2 (rows = d, cols = kv)
  __shared__ unsigned p_lds[4][512];          // per-wave [16 q][32 u32]
  const int orig = blockIdx.y*gridDim.x + blockIdx.x;   // grid (32, 64)
  const int id = ((orig & 7) << 8) + (orig >> 3);       // XCD swizzle, 2048 wgs
  const int qt = id & 31, bh = id >> 5;
  const int b = bh>>4, h = bh&15;
  const int t = threadIdx.x, w = t>>6, l = t&63, lg = l>>4, ll = l&15;
  const size_t kvbase = (size_t)bh*SEQN;

  // Q fragments (B-operand): chunks 0,1 = Qh, 2,3 = Ql
  bf16x8 qf[4];
  {
    size_t qrow = (kvbase + qt*64 + w*16 + ll) * 128;
#pragma unroll
    for (int i=0;i<4;i++)
      qf[i] = *(const bf16x8*)(Q + qrow + i*32 + lg*8);
  }
  f32x4 o[4];
#pragma unroll
  for (int d=0; d<4; d++) o[d] = (f32x4){0.f,0.f,0.f,0.f};
  float lsum = 0.f;

  auto stage = [&](int buf, int kv){
    int m0 = kv*64;
#pragma unroll
    for (int i=0;i<2;i++){   // K tile: [64][64] ush, 512 x 16B slots
      int s = t + i*256; int row = s>>3; int sl = s&7; int sl2 = sl ^ (row&7);
      async16(&k_lds[buf][s*8], Kh + (kvbase + m0 + row)*64 + sl2*8);
    }
#pragma unroll
    for (int i=0;i<2;i++){   // V tile: [64][64] ush, 512 x 16B slots
      int s = t + i*256; int row = s>>3; int sl = s&7; int sl2 = sl ^ (row&7);
      async16(&v_lds[buf][s*8], Vt + ((size_t)bh*64 + row)*SEQN + m0 + sl2*8);
    }
  };

  stage(0, 0);
  __syncthreads();
  const int NKV = SEQN/64;
  for (int kv=0; kv<NKV; ++kv){
    int cur = kv&1;
    if (kv+1 < NKV) stage(cur^1, kv+1);
    // scores (swapped): S^T frag = mfma(K, Q); lane: q=ll, kv=nt*16+lg*4+r
#pragma unroll
    for (int nt=0; nt<4; ++nt){
      int row = nt*16 + ll;
      bf16x8 kf0 = *(const bf16x8*)&k_lds[cur][row*64 + (((0*4+lg) ^ (row&7))*8)];
      bf16x8 kf1 = *(const bf16x8*)&k_lds[cur][row*64 + (((1*4+lg) ^ (row&7))*8)];
      f32x4 a = (f32x4){0.f,0.f,0.f,0.f};
      __builtin_amdgcn_s_setprio(1);
      a = __builtin_amdgcn_mfma_f32_16x16x32_bf16(kf0, qf[0], a, 0,0,0);
      a = __builtin_amdgcn_mfma_f32_16x16x32_bf16(kf1, qf[1], a, 0,0,0);
      a = __builtin_amdgcn_mfma_f32_16x16x32_bf16(kf0, qf[2], a, 0,0,0);
      a = __builtin_amdgcn_mfma_f32_16x16x32_bf16(kf1, qf[3], a, 0,0,0);
      __builtin_amdgcn_s_setprio(0);
      float e0 = exp2f(a[0]), e1 = exp2f(a[1]), e2 = exp2f(a[2]), e3 = exp2f(a[3]);
      lsum += (e0 + e1) + (e2 + e3);
      unsigned pk0 = cvt_pk_bf16(e0, e1);
      unsigned pk1 = cvt_pk_bf16(e2, e3);
      // u32 col c0 = nt*8+lg*2 (even): chunk = c0>>2, pos = c0&3
      int c0 = nt*8 + lg*2;
      int addr = ll*32 + (((c0>>2) ^ (ll&7))<<2) + (c0&3);
      *(uint2*)&p_lds[w][addr] = make_uint2(pk0, pk1);
    }
    // PV: o += P @ V
#pragma unroll
    for (int ks=0; ks<2; ++ks){
      int chunk = ks*4 + lg;
      bf16x8 pf = *(const bf16x8*)&p_lds[w][ll*32 + ((chunk ^ (ll&7))<<2)];
      __builtin_amdgcn_s_setprio(1);
#pragma unroll
      for (int dt=0; dt<4; ++dt){
        int row = dt*16 + ll;
        bf16x8 vf = *(const bf16x8*)&v_lds[cur][row*64 + (((ks*4+lg) ^ (row&7))*8)];
        o[dt] = __builtin_amdgcn_mfma_f32_16x16x32_bf16(pf, vf, o[dt], 0,0,0);
      }
      __builtin_amdgcn_s_setprio(0);
    }
    __syncthreads();
  }
  // softmax denominator: lane ll holds partial for q=ll; reduce across lg groups
  float tot = lsum;
  tot += __shfl_xor(tot, 16);
  tot += __shfl_xor(tot, 32);
  float inv = 1.0f / tot;
  // output: o[dt][r] is O[q=lg*4+r][d=dt*16+ll]; write hi|lo split directly
#pragma unroll
  for (int r=0;r<4;r++){
    float rl = __shfl(inv, lg*4 + r);
    int qrow = qt*64 + w*16 + lg*4 + r;
    size_t ob = ((size_t)(b*SEQN + qrow))*2048 + h*64;
#pragma unroll
    for (int dt=0; dt<4; ++dt){
      float f = o[dt][r] * rl;
      unsigned short hi = bf16_rtne(f);
      unsigned short lo = bf16_rtne(f - bf16f(hi));
      att_hl[ob + dt*16 + ll] = hi;
      att_hl[ob + 1024 + dt*16 + ll] = lo;
    }
  }
}

// ---------------------------------------------------------------------------
extern "C" void kernel_launch(void* const* d_in, const int* in_sizes, int n_in,
                              void* d_out, int out_size, void* d_ws, size_t ws_size,
                              hipStream_t stream){
  const float* x    = (const float*)d_in[0];
  const float* Wqkv = (const float*)d_in[1];
  const float* Wout = (const float*)d_in[2];
  const float* bout = (const float*)d_in[3];
  float* out = (float*)d_out;

  char* ws = (char*)d_ws;
  size_t off = 0;
  auto walloc = [&](size_t bytes) -> void* {
    void* p = ws + off; off += (bytes + 255) & ~(size_t)255; return p;
  };
  unsigned short* x_hl   = (unsigned short*)walloc((size_t)MROWS*2048*2);      // 33.5 MB
  unsigned short* wqkv_t = (unsigned short*)walloc((size_t)3072*2048*2);       // 12.6 MB
  float*          qkv    = (float*)walloc((size_t)MROWS*3072*4);               // 100.7 MB
  unsigned short* q_hl   = (unsigned short*)walloc((size_t)BH_TOT*SEQN*128*2); // 33.5 MB
  unsigned short* k_h    = (unsigned short*)walloc((size_t)BH_TOT*SEQN*64*2);  // 16.8 MB
  unsigned short* vt     = (unsigned short*)walloc((size_t)BH_TOT*64*SEQN*2);  // 16.8 MB
  unsigned short* wout_t = (unsigned short*)walloc((size_t)1024*2048*2);       // 4.2 MB
  unsigned short* att_hl = x_hl;    // alias: x_hl dead after QKV GEMM

  // 1) hi/lo split of x
  split_rows_k<<<8192, 256, 0, stream>>>(x, x_hl, MROWS, DIMC);
  // 2) transpose+split weights
  transpose_split_k<<<dim3(3072/32, 1024/32), 256, 0, stream>>>(Wqkv, wqkv_t, 1024, 3072);
  transpose_split_k<<<dim3(1024/32, 1024/32), 256, 0, stream>>>(Wout, wout_t, 1024, 1024);
  // 3) QKV projection: tiles 256x128 -> grid 32x24 = 768 blocks (3/CU exact)
  gemm_split_k<<<768, 512, 0, stream>>>(x_hl, wqkv_t, qkv, nullptr, MROWS, 3072, 1024);
  // 4) extract q (scaled hi/lo), k (hi) and V^T
  split_qk_k<<<(BH_TOT*SEQN*16)/256, 256, 0, stream>>>(qkv, q_hl, k_h);
  build_vt_k<<<dim3(SEQN/64, BH_TOT), 256, 0, stream>>>(qkv, vt);
  // 5) attention (epilogue writes hi/lo split directly)
  attn_k<<<dim3(SEQN/64, BH_TOT), 256, 0, stream>>>(q_hl, k_h, vt, att_hl);
  // 6) output projection + bias: grid 32x8 = 256 blocks
  gemm_split_k<<<256, 512, 0, stream>>>(att_hl, wout_t, out, bout, MROWS, 1024, 1024);
}

// Round 7
// 556.797 us; speedup vs baseline: 1.1301x; 1.0048x over previous
//
#include <hip/hip_runtime.h>
#include <hip/hip_bf16.h>
#include <stdint.h>

// Problem constants
#define BATCH 4
#define SEQN  2048
#define DIMC  1024
#define NHEADS 16
#define DHEAD 64
#define BH_TOT 64          // BATCH*NHEADS
#define MROWS 8192         // BATCH*SEQN

typedef __attribute__((ext_vector_type(8))) short bf16x8;
typedef __attribute__((ext_vector_type(4))) float f32x4;

__device__ __forceinline__ unsigned short bf16_rtne(float f){
  union { float f; unsigned u; } v; v.f = f;
  unsigned u = v.u;
  return (unsigned short)((u + 0x7FFFu + ((u >> 16) & 1u)) >> 16);
}
__device__ __forceinline__ float bf16f(unsigned short h){
  union { unsigned u; float f; } v; v.u = ((unsigned)h) << 16;
  return v.f;
}
__device__ __forceinline__ unsigned cvt_pk_bf16(float lo, float hi){
  unsigned r;
  asm("v_cvt_pk_bf16_f32 %0, %1, %2" : "=v"(r) : "v"(lo), "v"(hi));
  return r;
}

__device__ __forceinline__ void async16(void* lds, const void* g){
  __builtin_amdgcn_global_load_lds((const __attribute__((address_space(1))) void*)g,
                                   (__attribute__((address_space(3))) void*)lds, 16, 0, 0);
}

// ---------------------------------------------------------------------------
// C1: split fp32 rows [nrows][Kc] -> bf16 [nrows][2*Kc] = [hi | lo]
// ---------------------------------------------------------------------------
__global__ __launch_bounds__(256) void split_rows_k(const float* __restrict__ X,
    unsigned short* __restrict__ O, int nrows, int Kc){
  int q4 = Kc >> 2;
  int total = nrows * q4;
  int idx = blockIdx.x*256 + threadIdx.x;
  if (idx >= total) return;
  int row = idx / q4, c = idx - row*q4;
  const float4 v = *(const float4*)(X + ((size_t)row*Kc + c*4));
  float fv[4] = {v.x, v.y, v.z, v.w};
  unsigned short hi[4], lo[4];
#pragma unroll
  for (int j=0;j<4;j++){ hi[j] = bf16_rtne(fv[j]); lo[j] = bf16_rtne(fv[j] - bf16f(hi[j])); }
  size_t ob = (size_t)row*(2*Kc) + c*4;
  ushort4 h; h.x=hi[0]; h.y=hi[1]; h.z=hi[2]; h.w=hi[3];
  ushort4 l2; l2.x=lo[0]; l2.y=lo[1]; l2.z=lo[2]; l2.w=lo[3];
  *(ushort4*)(O + ob) = h;
  *(ushort4*)(O + ob + Kc) = l2;
}

// ---------------------------------------------------------------------------
// C2: transpose + split: W [K][Nc] f32 -> Wt [Nc][2K] bf16 (hi | lo)
// ---------------------------------------------------------------------------
__global__ __launch_bounds__(256) void transpose_split_k(const float* __restrict__ W,
    unsigned short* __restrict__ Wt, int K, int Nc){
  __shared__ float tile[32][33];
  int tx = threadIdx.x & 31, ty = threadIdx.x >> 5;   // 32 x 8
  int n0 = blockIdx.x*32, k0 = blockIdx.y*32;
#pragma unroll
  for (int i=0;i<4;i++){
    int k = k0 + ty + i*8;
    tile[ty + i*8][tx] = W[(size_t)k*Nc + n0 + tx];
  }
  __syncthreads();
#pragma unroll
  for (int i=0;i<4;i++){
    int n = n0 + ty + i*8;
    float f = tile[tx][ty + i*8];
    unsigned short hi = bf16_rtne(f);
    unsigned short lo = bf16_rtne(f - bf16f(hi));
    Wt[(size_t)n*(2*K) + k0 + tx] = hi;
    Wt[(size_t)n*(2*K) + K + k0 + tx] = lo;
  }
}

// ---------------------------------------------------------------------------
// Split-bf16 GEMM, m201-style phase schedule.
//   A [M][2K] = [Ah|Al], Bt [Nc][2K] = [Bh|Bl]; virtual K' = 3K.
// BM=128, BN=256, BK=64. 512 threads = 8 waves (2M x 4N); wave C = 64x64.
// LDS 96KB: A 2buf x 16KB, B 2buf x 32KB (buf = kt&1). Identity 1KB blocks
// (lane l at l*16B -> 0 bank conflicts; global source carries permutation).
// Per K-tile, 2 phases:
//  q0: [vmcnt(4); s_barrier]  (counted: retires A(kt)+B(kt), keeps B(kt+1))
//      ds_read 8 B-frags + 4 A-frags; stage A(kt+1) [2 loads];
//      setprio1; 16 MFMA; setprio0; s_barrier
//  q1: ds_read 4 A-frags; stage B(kt+2) [4 loads];
//      setprio1; 16 MFMA; setprio0   (boundary barrier closes the phase)
// Race-freedom: B region freed after q0 (B-reads front-loaded) -> B(kt+2)
// staging at q1 safe; A region of buf 1-P freed at the kt boundary -> A(kt+1)
// staging at q0 safe. vmcnt never 0 mid-loop (T4). No sched_barrier (m141).
// ---------------------------------------------------------------------------
__global__ __launch_bounds__(512, 2) void gemm_split_k(
    const unsigned short* __restrict__ A, const unsigned short* __restrict__ Bt,
    float* __restrict__ C, const float* __restrict__ bias, int M, int Nc, int K)
{
  __shared__ unsigned short a_lds[2][8192];    // [buf][(f*2+kk)*512 + l*8], 128r x 64k
  __shared__ unsigned short b_lds[2][16384];   // [buf][g*8192 + (fl*2+kk)*512 + l*8], 256r x 64k
  const int t = threadIdx.x, wid = t>>6, l = t&63, lg = l>>4, ll = l&15;
  const int wm = wid>>2, wn = wid&3;           // 2(M) x 4(N)
  const int nbm = M>>7;
  const int nwg = nbm*(Nc>>8);
  const int orig = blockIdx.x;
  const int id = ((orig&7)*(nwg>>3)) + (orig>>3);   // XCD swizzle (nwg%8==0)
  const int m0 = (id % nbm)<<7, n0 = (id / nbm)<<8;
  const int ldk = 2*K;
  const int nkt = (3*K)>>6;                    // 48 K-tiles of 64

  f32x4 acc[4][4];
#pragma unroll
  for (int i=0;i<4;i++)
#pragma unroll
    for (int j=0;j<4;j++) acc[i][j] = (f32x4){0.f,0.f,0.f,0.f};

  // stage A K-tile kt (128 x 64, 16 KB) -> buf kt&1. 2 loads/thread.
  auto stageA = [&](int kt){
    const int kp = kt<<6;
    const int ac = (kp < K) ? kp : kp - K;     // A: Ah,Ah,Al
    const int buf = kt&1;
#pragma unroll
    for (int i=0;i<2;i++){
      int s = i*512 + t;                       // slot: block b=s>>6 (f=b>>1,kk=b&1), lane=l
      int f = s>>7, kk = (s>>6)&1;
      async16(&a_lds[buf][s*8],
              A + (size_t)(m0 + f*16 + ll)*ldk + ac + kk*32 + lg*8);
    }
  };
  // stage B K-tile kt (256 x 64, 32 KB = 2 halves) -> buf kt&1. 4 loads/thread.
  auto stageB = [&](int kt){
    const int kp = kt<<6;
    const int bc = (kp < 2*K) ? kp : kp - 2*K; // B: Bh,Bl,Bh
    const int buf = kt&1;
#pragma unroll
    for (int g=0; g<2; g++)
#pragma unroll
      for (int i=0;i<2;i++){
        int s = i*512 + t;
        int fl = s>>7, kk = (s>>6)&1;
        async16(&b_lds[buf][g*8192 + s*8],
                Bt + (size_t)(n0 + g*128 + fl*16 + ll)*ldk + bc + kk*32 + lg*8);
      }
  };

  // Prologue issue order (defines vmcnt retirement order): B(0), A(0), B(1).
  stageB(0); stageA(0); stageB(1);

  const int bg = wn>>1, bfl0 = (wn&1)*4;       // wave's B half / local frag base

  for (int kt=0; kt<nkt; ++kt){
    const int buf = kt&1;
    // K-tile boundary: retire A(kt) (and older); keep B(kt+1) in flight.
    if (kt < nkt-1) asm volatile("s_waitcnt vmcnt(4)\ns_barrier" ::: "memory");
    else            asm volatile("s_waitcnt vmcnt(0)\ns_barrier" ::: "memory");

    // ---- phase 0 ----
    bf16x8 bfr[4][2];
#pragma unroll
    for (int j=0;j<4;j++)
#pragma unroll
      for (int kk=0;kk<2;kk++)
        bfr[j][kk] = *(const bf16x8*)&b_lds[buf][bg*8192 + ((bfl0+j)*2+kk)*512 + l*8];
    bf16x8 af0[2][2];
#pragma unroll
    for (int i=0;i<2;i++)
#pragma unroll
      for (int kk=0;kk<2;kk++)
        af0[i][kk] = *(const bf16x8*)&a_lds[buf][((wm*4+i)*2+kk)*512 + l*8];
    if (kt+1 < nkt) stageA(kt+1);
    __builtin_amdgcn_s_setprio(1);
#pragma unroll
    for (int i=0;i<2;i++)
#pragma unroll
      for (int kk=0;kk<2;kk++)
#pragma unroll
        for (int j=0;j<4;j++)
          acc[i][j] = __builtin_amdgcn_mfma_f32_16x16x32_bf16(af0[i][kk], bfr[j][kk], acc[i][j], 0,0,0);
    __builtin_amdgcn_s_setprio(0);
    asm volatile("s_barrier" ::: "memory");

    // ---- phase 1 ----
    bf16x8 af1[2][2];
#pragma unroll
    for (int i=0;i<2;i++)
#pragma unroll
      for (int kk=0;kk<2;kk++)
        af1[i][kk] = *(const bf16x8*)&a_lds[buf][((wm*4+2+i)*2+kk)*512 + l*8];
    if (kt+2 < nkt) stageB(kt+2);
    __builtin_amdgcn_s_setprio(1);
#pragma unroll
    for (int i=0;i<2;i++)
#pragma unroll
      for (int kk=0;kk<2;kk++)
#pragma unroll
        for (int j=0;j<4;j++)
          acc[2+i][j] = __builtin_amdgcn_mfma_f32_16x16x32_bf16(af1[i][kk], bfr[j][kk], acc[2+i][j], 0,0,0);
    __builtin_amdgcn_s_setprio(0);
    // boundary [vmcnt; s_barrier] of the next tile closes this phase.
  }

#pragma unroll
  for (int mf=0;mf<4;mf++)
#pragma unroll
    for (int j=0;j<4;j++){
      int col = n0 + (wn*4+j)*16 + ll;
      float bv = bias ? bias[col] : 0.f;
#pragma unroll
      for (int r=0;r<4;r++){
        int row = m0 + (wm*4+mf)*16 + lg*4 + r;
        C[(size_t)row*Nc + col] = acc[mf][j][r] + bv;
      }
    }
}

// ---------------------------------------------------------------------------
// C4a: qkv f32 [B*N][3072] -> q_hl [BH][N][128] (hi|lo of SCALED q),
//                            k_h  [BH][N][64]  (hi only)
// Q prescaled by 0.125*log2(e) so attention uses exp2 directly.
// ---------------------------------------------------------------------------
#define QSCALE 0.18033688f
__global__ __launch_bounds__(256) void split_qk_k(const float* __restrict__ qkv,
    unsigned short* __restrict__ Qo, unsigned short* __restrict__ Ko){
  int idx = blockIdx.x*256 + threadIdx.x;      // BH*N*16 threads exactly
  int d4 = idx & 15, n = (idx>>4) & (SEQN-1), bh = idx >> 15;
  int b = bh>>4, h = bh&15;
  size_t base = ((size_t)(b*SEQN + n))*3072 + h*64 + d4*4;
  float4 q = *(const float4*)(qkv + base);
  float4 k = *(const float4*)(qkv + base + 1024);
  float fq[4] = {q.x*QSCALE, q.y*QSCALE, q.z*QSCALE, q.w*QSCALE};
  float fk[4] = {k.x, k.y, k.z, k.w};
  unsigned short qh[4], ql[4], kh[4];
#pragma unroll
  for (int j=0;j<4;j++){
    qh[j] = bf16_rtne(fq[j]); ql[j] = bf16_rtne(fq[j] - bf16f(qh[j]));
    kh[j] = bf16_rtne(fk[j]);
  }
  size_t obq = ((size_t)bh*SEQN + n)*128 + d4*4;
  size_t obk = ((size_t)bh*SEQN + n)*64 + d4*4;
  ushort4 u;
  u.x=qh[0];u.y=qh[1];u.z=qh[2];u.w=qh[3]; *(ushort4*)(Qo+obq) = u;
  u.x=ql[0];u.y=ql[1];u.z=ql[2];u.w=ql[3]; *(ushort4*)(Qo+obq+64) = u;
  u.x=kh[0];u.y=kh[1];u.z=kh[2];u.w=kh[3]; *(ushort4*)(Ko+obk) = u;
}

// ---------------------------------------------------------------------------
// C4b: V transpose: qkv -> Vt bf16 [BH][DHEAD][SEQN]
// ---------------------------------------------------------------------------
__global__ __launch_bounds__(256) void build_vt_k(const float* __restrict__ qkv,
    unsigned short* __restrict__ Vt){
  __shared__ float tile[64][65];
  const int mt = blockIdx.x, bh = blockIdx.y;
  const int b = bh>>4, h = bh&15;
  const int t = threadIdx.x;
  const int r = t>>2, seg = t&3;
  size_t src = ((size_t)(b*SEQN + mt*64 + r))*3072 + 2048 + h*64 + seg*16;
#pragma unroll
  for (int j=0;j<4;j++){
    float4 v = *(const float4*)(qkv + src + j*4);
    tile[r][seg*16 + j*4 + 0] = v.x;
    tile[r][seg*16 + j*4 + 1] = v.y;
    tile[r][seg*16 + j*4 + 2] = v.z;
    tile[r][seg*16 + j*4 + 3] = v.w;
  }
  __syncthreads();
  const int d = r, ms = seg;
  unsigned short o16[16];
#pragma unroll
  for (int j=0;j<16;j++) o16[j] = bf16_rtne(tile[ms*16 + j][d]);
  size_t dst = ((size_t)(bh*64 + d))*SEQN + mt*64 + ms*16;
  uint4 u0, u1;
  unsigned* pu = (unsigned*)&u0;
  unsigned* pv = (unsigned*)&u1;
#pragma unroll
  for (int j=0;j<4;j++){
    pu[j] = (unsigned)o16[2*j]   | ((unsigned)o16[2*j+1]<<16);
    pv[j] = (unsigned)o16[8+2*j] | ((unsigned)o16[9+2*j]<<16);
  }
  *(uint4*)(Vt + dst) = u0;
  *(uint4*)(Vt + dst + 8) = u1;
}

// ---------------------------------------------------------------------------
// K2: flash attention, swapped QK^T. S = (Qh+Ql)·Kh.
// Epilogue FUSED with the hi/lo split: writes att_hl [row][2048] directly.
// ---------------------------------------------------------------------------
__global__ __launch_bounds__(256, 4) void attn_k(const unsigned short* __restrict__ Q,
    const unsigned short* __restrict__ Kh, const unsigned short* __restrict__ Vt,
    unsigned short* __restrict__ att_hl)
{
  __shared__ unsigned short k_lds[2][4096];   // [64][64] x2
  __shared__ unsigned short v_lds[2][4096];   // [64][64] x2 (rows = d, cols = kv)
  __shared__ unsigned p_lds[4][512];          // per-wave [16 q][32 u32]
  const int orig = blockIdx.y*gridDim.x + blockIdx.x;   // grid (32, 64)
  const int id = ((orig & 7) << 8) + (orig >> 3);       // XCD swizzle, 2048 wgs
  const int qt = id & 31, bh = id >> 5;
  const int b = bh>>4, h = bh&15;
  const int t = threadIdx.x, w = t>>6, l = t&63, lg = l>>4, ll = l&15;
  const size_t kvbase = (size_t)bh*SEQN;

  // Q fragments (B-operand): chunks 0,1 = Qh, 2,3 = Ql
  bf16x8 qf[4];
  {
    size_t qrow = (kvbase + qt*64 + w*16 + ll) * 128;
#pragma unroll
    for (int i=0;i<4;i++)
      qf[i] = *(const bf16x8*)(Q + qrow + i*32 + lg*8);
  }
  f32x4 o[4];
#pragma unroll
  for (int d=0; d<4; d++) o[d] = (f32x4){0.f,0.f,0.f,0.f};
  float lsum = 0.f;

  auto stage = [&](int buf, int kv){
    int m0 = kv*64;
#pragma unroll
    for (int i=0;i<2;i++){   // K tile: [64][64] ush, 512 x 16B slots
      int s = t + i*256; int row = s>>3; int sl = s&7; int sl2 = sl ^ (row&7);
      async16(&k_lds[buf][s*8], Kh + (kvbase + m0 + row)*64 + sl2*8);
    }
#pragma unroll
    for (int i=0;i<2;i++){   // V tile: [64][64] ush, 512 x 16B slots
      int s = t + i*256; int row = s>>3; int sl = s&7; int sl2 = sl ^ (row&7);
      async16(&v_lds[buf][s*8], Vt + ((size_t)bh*64 + row)*SEQN + m0 + sl2*8);
    }
  };

  stage(0, 0);
  __syncthreads();
  const int NKV = SEQN/64;
  for (int kv=0; kv<NKV; ++kv){
    int cur = kv&1;
    if (kv+1 < NKV) stage(cur^1, kv+1);
    // scores (swapped): S^T frag = mfma(K, Q); lane: q=ll, kv=nt*16+lg*4+r
#pragma unroll
    for (int nt=0; nt<4; ++nt){
      int row = nt*16 + ll;
      bf16x8 kf0 = *(const bf16x8*)&k_lds[cur][row*64 + (((0*4+lg) ^ (row&7))*8)];
      bf16x8 kf1 = *(const bf16x8*)&k_lds[cur][row*64 + (((1*4+lg) ^ (row&7))*8)];
      f32x4 a = (f32x4){0.f,0.f,0.f,0.f};
      __builtin_amdgcn_s_setprio(1);
      a = __builtin_amdgcn_mfma_f32_16x16x32_bf16(kf0, qf[0], a, 0,0,0);
      a = __builtin_amdgcn_mfma_f32_16x16x32_bf16(kf1, qf[1], a, 0,0,0);
      a = __builtin_amdgcn_mfma_f32_16x16x32_bf16(kf0, qf[2], a, 0,0,0);
      a = __builtin_amdgcn_mfma_f32_16x16x32_bf16(kf1, qf[3], a, 0,0,0);
      __builtin_amdgcn_s_setprio(0);
      float e0 = exp2f(a[0]), e1 = exp2f(a[1]), e2 = exp2f(a[2]), e3 = exp2f(a[3]);
      lsum += (e0 + e1) + (e2 + e3);
      unsigned pk0 = cvt_pk_bf16(e0, e1);
      unsigned pk1 = cvt_pk_bf16(e2, e3);
      // u32 col c0 = nt*8+lg*2 (even): chunk = c0>>2, pos = c0&3
      int c0 = nt*8 + lg*2;
      int addr = ll*32 + (((c0>>2) ^ (ll&7))<<2) + (c0&3);
      *(uint2*)&p_lds[w][addr] = make_uint2(pk0, pk1);
    }
    // PV: o += P @ V
#pragma unroll
    for (int ks=0; ks<2; ++ks){
      int chunk = ks*4 + lg;
      bf16x8 pf = *(const bf16x8*)&p_lds[w][ll*32 + ((chunk ^ (ll&7))<<2)];
      __builtin_amdgcn_s_setprio(1);
#pragma unroll
      for (int dt=0; dt<4; ++dt){
        int row = dt*16 + ll;
        bf16x8 vf = *(const bf16x8*)&v_lds[cur][row*64 + (((ks*4+lg) ^ (row&7))*8)];
        o[dt] = __builtin_amdgcn_mfma_f32_16x16x32_bf16(pf, vf, o[dt], 0,0,0);
      }
      __builtin_amdgcn_s_setprio(0);
    }
    __syncthreads();
  }
  // softmax denominator: lane ll holds partial for q=ll; reduce across lg groups
  float tot = lsum;
  tot += __shfl_xor(tot, 16);
  tot += __shfl_xor(tot, 32);
  float inv = 1.0f / tot;
  // output: o[dt][r] is O[q=lg*4+r][d=dt*16+ll]; write hi|lo split directly
#pragma unroll
  for (int r=0;r<4;r++){
    float rl = __shfl(inv, lg*4 + r);
    int qrow = qt*64 + w*16 + lg*4 + r;
    size_t ob = ((size_t)(b*SEQN + qrow))*2048 + h*64;
#pragma unroll
    for (int dt=0; dt<4; ++dt){
      float f = o[dt][r] * rl;
      unsigned short hi = bf16_rtne(f);
      unsigned short lo = bf16_rtne(f - bf16f(hi));
      att_hl[ob + dt*16 + ll] = hi;
      att_hl[ob + 1024 + dt*16 + ll] = lo;
    }
  }
}

// ---------------------------------------------------------------------------
extern "C" void kernel_launch(void* const* d_in, const int* in_sizes, int n_in,
                              void* d_out, int out_size, void* d_ws, size_t ws_size,
                              hipStream_t stream){
  const float* x    = (const float*)d_in[0];
  const float* Wqkv = (const float*)d_in[1];
  const float* Wout = (const float*)d_in[2];
  const float* bout = (const float*)d_in[3];
  float* out = (float*)d_out;

  char* ws = (char*)d_ws;
  size_t off = 0;
  auto walloc = [&](size_t bytes) -> void* {
    void* p = ws + off; off += (bytes + 255) & ~(size_t)255; return p;
  };
  unsigned short* x_hl   = (unsigned short*)walloc((size_t)MROWS*2048*2);      // 33.5 MB
  unsigned short* wqkv_t = (unsigned short*)walloc((size_t)3072*2048*2);       // 12.6 MB
  float*          qkv    = (float*)walloc((size_t)MROWS*3072*4);               // 100.7 MB
  unsigned short* q_hl   = (unsigned short*)walloc((size_t)BH_TOT*SEQN*128*2); // 33.5 MB
  unsigned short* k_h    = (unsigned short*)walloc((size_t)BH_TOT*SEQN*64*2);  // 16.8 MB
  unsigned short* vt     = (unsigned short*)walloc((size_t)BH_TOT*64*SEQN*2);  // 16.8 MB
  unsigned short* wout_t = (unsigned short*)walloc((size_t)1024*2048*2);       // 4.2 MB
  unsigned short* att_hl = x_hl;    // alias: x_hl dead after QKV GEMM

  // 1) hi/lo split of x
  split_rows_k<<<8192, 256, 0, stream>>>(x, x_hl, MROWS, DIMC);
  // 2) transpose+split weights
  transpose_split_k<<<dim3(3072/32, 1024/32), 256, 0, stream>>>(Wqkv, wqkv_t, 1024, 3072);
  transpose_split_k<<<dim3(1024/32, 1024/32), 256, 0, stream>>>(Wout, wout_t, 1024, 1024);
  // 3) QKV projection: 128x256 tiles -> grid 64x12 = 768 blocks (3 full rounds)
  gemm_split_k<<<768, 512, 0, stream>>>(x_hl, wqkv_t, qkv, nullptr, MROWS, 3072, 1024);
  // 4) extract q (scaled hi/lo), k (hi) and V^T
  split_qk_k<<<(BH_TOT*SEQN*16)/256, 256, 0, stream>>>(qkv, q_hl, k_h);
  build_vt_k<<<dim3(SEQN/64, BH_TOT), 256, 0, stream>>>(qkv, vt);
  // 5) attention (epilogue writes hi/lo split directly)
  attn_k<<<dim3(SEQN/64, BH_TOT), 256, 0, stream>>>(q_hl, k_h, vt, att_hl);
  // 6) output projection + bias: 128x256 tiles -> grid 64x4 = 256 blocks (1 round)
  gemm_split_k<<<256, 512, 0, stream>>>(att_hl, wout_t, out, bout, MROWS, 1024, 1024);
}

// Round 11
// 524.468 us; speedup vs baseline: 1.1998x; 1.0616x over previous
//
#include <hip/hip_runtime.h>
#include <hip/hip_bf16.h>
#include <stdint.h>

// Problem constants
#define BATCH 4
#define SEQN  2048
#define DIMC  1024
#define NHEADS 16
#define DHEAD 64
#define BH_TOT 64          // BATCH*NHEADS
#define MROWS 8192         // BATCH*SEQN

typedef __attribute__((ext_vector_type(8))) short bf16x8;
typedef __attribute__((ext_vector_type(4))) float f32x4;

__device__ __forceinline__ unsigned short bf16_rtne(float f){
  union { float f; unsigned u; } v; v.f = f;
  unsigned u = v.u;
  return (unsigned short)((u + 0x7FFFu + ((u >> 16) & 1u)) >> 16);
}
__device__ __forceinline__ float bf16f(unsigned short h){
  union { unsigned u; float f; } v; v.u = ((unsigned)h) << 16;
  return v.f;
}
__device__ __forceinline__ unsigned cvt_pk_bf16(float lo, float hi){
  unsigned r;
  asm("v_cvt_pk_bf16_f32 %0, %1, %2" : "=v"(r) : "v"(lo), "v"(hi));
  return r;
}

__device__ __forceinline__ void async16(void* lds, const void* g){
  __builtin_amdgcn_global_load_lds((const __attribute__((address_space(1))) void*)g,
                                   (__attribute__((address_space(3))) void*)lds, 16, 0, 0);
}

// ---------------------------------------------------------------------------
// C1: round fp32 rows [nrows][Kc] -> bf16 hi only [nrows][Kc]
// ---------------------------------------------------------------------------
__global__ __launch_bounds__(256) void round_rows_k(const float* __restrict__ X,
    unsigned short* __restrict__ O, int nrows, int Kc){
  int q8 = Kc >> 3;
  int total = nrows * q8;
  int idx = blockIdx.x*256 + threadIdx.x;
  if (idx >= total) return;
  size_t base = (size_t)idx * 8;
  const float4 v0 = *(const float4*)(X + base);
  const float4 v1 = *(const float4*)(X + base + 4);
  float fv[8] = {v0.x,v0.y,v0.z,v0.w,v1.x,v1.y,v1.z,v1.w};
  uint4 u;
  unsigned* pu = (unsigned*)&u;
#pragma unroll
  for (int j=0;j<4;j++)
    pu[j] = (unsigned)bf16_rtne(fv[2*j]) | ((unsigned)bf16_rtne(fv[2*j+1])<<16);
  *(uint4*)(O + base) = u;
}

// ---------------------------------------------------------------------------
// C2: transpose + split: W [K][Nc] f32 -> Wt [Nc][2K] bf16 (hi | lo)
// ---------------------------------------------------------------------------
__global__ __launch_bounds__(256) void transpose_split_k(const float* __restrict__ W,
    unsigned short* __restrict__ Wt, int K, int Nc){
  __shared__ float tile[32][33];
  int tx = threadIdx.x & 31, ty = threadIdx.x >> 5;   // 32 x 8
  int n0 = blockIdx.x*32, k0 = blockIdx.y*32;
#pragma unroll
  for (int i=0;i<4;i++){
    int k = k0 + ty + i*8;
    tile[ty + i*8][tx] = W[(size_t)k*Nc + n0 + tx];
  }
  __syncthreads();
#pragma unroll
  for (int i=0;i<4;i++){
    int n = n0 + ty + i*8;
    float f = tile[tx][ty + i*8];
    unsigned short hi = bf16_rtne(f);
    unsigned short lo = bf16_rtne(f - bf16f(hi));
    Wt[(size_t)n*(2*K) + k0 + tx] = hi;
    Wt[(size_t)n*(2*K) + K + k0 + tx] = lo;
  }
}

// ---------------------------------------------------------------------------
// 2-segment split GEMM: C = Ah @ (Bh + Bl)   (error = Al·B ~ 0.08% rel)
//   A [M][K] bf16 hi only; Bt [Nc][2K] = [Bh|Bl]; virtual K' = 2K.
// r4-proven m97 structure: 128x128 tile, BK=32, 4 waves, 2-buf LDS,
// stage-next -> read -> 16 MFMA -> __syncthreads. Identity-block LDS
// (block f = 16 rows x 32 cols = 1KB; lane l owns slot l*16B; global src
// carries the permutation) -> 0 bank conflicts (verified r5-r7).
// ---------------------------------------------------------------------------
__global__ __launch_bounds__(256) void gemm_h_k(
    const unsigned short* __restrict__ A, const unsigned short* __restrict__ Bt,
    float* __restrict__ C, const float* __restrict__ bias, int M, int Nc, int K)
{
  __shared__ unsigned short a_lds[2][4096];  // 8 blocks x 512 ush
  __shared__ unsigned short b_lds[2][4096];
  const int t = threadIdx.x, w = t>>6, l = t&63, lg = l>>4, ll = l&15;
  const int wr = w>>1, wc = w&1;
  const int nbx = gridDim.x;
  const int nwg = nbx * gridDim.y;
  const int orig = blockIdx.y*nbx + blockIdx.x;
  const int id = ((orig & 7) * (nwg >> 3)) + (orig >> 3);   // XCD swizzle
  const int m0 = (id % nbx)*128, n0 = (id / nbx)*128;
  const int ldk = 2*K;
  const int nkt = (2*K) >> 5;                // 64 K-tiles of 32
  f32x4 acc[4][4];
#pragma unroll
  for (int m=0;m<4;m++)
#pragma unroll
    for (int n=0;n<4;n++) acc[m][n] = (f32x4){0.f,0.f,0.f,0.f};

  auto stage = [&](int buf, int kt){
    int kp = kt*32;
    int ac = (kp < K) ? kp : kp - K;         // A: Ah,Ah  (hi-only storage)
    int bc = kp;                             // B: Bh,Bl  (direct)
#pragma unroll
    for (int i=0;i<2;i++){
      int s = i*256 + t;                     // slot: block=s>>6, row=(s&15), chunk=(s>>4)&3
      async16(&a_lds[buf][s*8],
              A + (size_t)(m0 + (s>>6)*16 + (s&15))*K + ac + ((s>>4)&3)*8);
    }
#pragma unroll
    for (int i=0;i<2;i++){
      int s = i*256 + t;
      async16(&b_lds[buf][s*8],
              Bt + (size_t)(n0 + (s>>6)*16 + (s&15))*ldk + bc + ((s>>4)&3)*8);
    }
  };

  stage(0, 0);
  __syncthreads();
  for (int kt=0; kt<nkt; ++kt){
    int cur = kt&1;
    if (kt+1 < nkt) stage(cur^1, kt+1);
    bf16x8 af[4], bfr[4];
#pragma unroll
    for (int m=0;m<4;m++)
      af[m] = *(const bf16x8*)&a_lds[cur][(wr*4+m)*512 + l*8];
#pragma unroll
    for (int n=0;n<4;n++)
      bfr[n] = *(const bf16x8*)&b_lds[cur][(wc*4+n)*512 + l*8];
#pragma unroll
    for (int m=0;m<4;m++)
#pragma unroll
      for (int n=0;n<4;n++)
        acc[m][n] = __builtin_amdgcn_mfma_f32_16x16x32_bf16(af[m], bfr[n], acc[m][n], 0,0,0);
    __syncthreads();
  }
#pragma unroll
  for (int m=0;m<4;m++)
#pragma unroll
    for (int n=0;n<4;n++){
      int col = n0 + wc*64 + n*16 + ll;
      float bv = bias ? bias[col] : 0.f;
#pragma unroll
      for (int r=0;r<4;r++){
        int row = m0 + wr*64 + m*16 + lg*4 + r;
        C[(size_t)row*Nc + col] = acc[m][n][r] + bv;
      }
    }
}

// ---------------------------------------------------------------------------
// C4a: qkv f32 [B*N][3072] -> q_hl [BH][N][128] (hi|lo of SCALED q),
//                            k_h  [BH][N][64]  (hi only)
// Q prescaled by 0.125*log2(e) so attention uses exp2 directly.
// ---------------------------------------------------------------------------
#define QSCALE 0.18033688f
__global__ __launch_bounds__(256) void split_qk_k(const float* __restrict__ qkv,
    unsigned short* __restrict__ Qo, unsigned short* __restrict__ Ko){
  int idx = blockIdx.x*256 + threadIdx.x;      // BH*N*16 threads exactly
  int d4 = idx & 15, n = (idx>>4) & (SEQN-1), bh = idx >> 15;
  int b = bh>>4, h = bh&15;
  size_t base = ((size_t)(b*SEQN + n))*3072 + h*64 + d4*4;
  float4 q = *(const float4*)(qkv + base);
  float4 k = *(const float4*)(qkv + base + 1024);
  float fq[4] = {q.x*QSCALE, q.y*QSCALE, q.z*QSCALE, q.w*QSCALE};
  float fk[4] = {k.x, k.y, k.z, k.w};
  unsigned short qh[4], ql[4], kh[4];
#pragma unroll
  for (int j=0;j<4;j++){
    qh[j] = bf16_rtne(fq[j]); ql[j] = bf16_rtne(fq[j] - bf16f(qh[j]));
    kh[j] = bf16_rtne(fk[j]);
  }
  size_t obq = ((size_t)bh*SEQN + n)*128 + d4*4;
  size_t obk = ((size_t)bh*SEQN + n)*64 + d4*4;
  ushort4 u;
  u.x=qh[0];u.y=qh[1];u.z=qh[2];u.w=qh[3]; *(ushort4*)(Qo+obq) = u;
  u.x=ql[0];u.y=ql[1];u.z=ql[2];u.w=ql[3]; *(ushort4*)(Qo+obq+64) = u;
  u.x=kh[0];u.y=kh[1];u.z=kh[2];u.w=kh[3]; *(ushort4*)(Ko+obk) = u;
}

// ---------------------------------------------------------------------------
// C4b: V transpose: qkv -> Vt bf16 [BH][DHEAD][SEQN]
// ---------------------------------------------------------------------------
__global__ __launch_bounds__(256) void build_vt_k(const float* __restrict__ qkv,
    unsigned short* __restrict__ Vt){
  __shared__ float tile[64][65];
  const int mt = blockIdx.x, bh = blockIdx.y;
  const int b = bh>>4, h = bh&15;
  const int t = threadIdx.x;
  const int r = t>>2, seg = t&3;
  size_t src = ((size_t)(b*SEQN + mt*64 + r))*3072 + 2048 + h*64 + seg*16;
#pragma unroll
  for (int j=0;j<4;j++){
    float4 v = *(const float4*)(qkv + src + j*4);
    tile[r][seg*16 + j*4 + 0] = v.x;
    tile[r][seg*16 + j*4 + 1] = v.y;
    tile[r][seg*16 + j*4 + 2] = v.z;
    tile[r][seg*16 + j*4 + 3] = v.w;
  }
  __syncthreads();
  const int d = r, ms = seg;
  unsigned short o16[16];
#pragma unroll
  for (int j=0;j<16;j++) o16[j] = bf16_rtne(tile[ms*16 + j][d]);
  size_t dst = ((size_t)(bh*64 + d))*SEQN + mt*64 + ms*16;
  uint4 u0, u1;
  unsigned* pu = (unsigned*)&u0;
  unsigned* pv = (unsigned*)&u1;
#pragma unroll
  for (int j=0;j<4;j++){
    pu[j] = (unsigned)o16[2*j]   | ((unsigned)o16[2*j+1]<<16);
    pv[j] = (unsigned)o16[8+2*j] | ((unsigned)o16[9+2*j]<<16);
  }
  *(uint4*)(Vt + dst) = u0;
  *(uint4*)(Vt + dst + 8) = u1;
}

// ---------------------------------------------------------------------------
// K2: flash attention, swapped QK^T, 128 q-rows per block (2 sub-tiles per
// wave sharing the K/V LDS reads -> K/V HBM traffic halves, 2x compute per
// staged tile hides load latency). S = (Qh+Ql)·Kh. Epilogue writes att_h
// (bf16 hi only) for the 2-segment out-projection.
// LDS: K 2x8KB + V 2x8KB + P 4x2x2KB = 48KB -> 3 blocks/CU.
// ---------------------------------------------------------------------------
__global__ __launch_bounds__(256) void attn_k(const unsigned short* __restrict__ Q,
    const unsigned short* __restrict__ Kh, const unsigned short* __restrict__ Vt,
    unsigned short* __restrict__ att_h)
{
  __shared__ unsigned short k_lds[2][4096];   // [64][64] x2
  __shared__ unsigned short v_lds[2][4096];   // [64][64] x2 (rows = d, cols = kv)
  __shared__ unsigned p_lds[4][2][512];       // per-wave, per-sub [16 q][32 u32]
  const int orig = blockIdx.y*gridDim.x + blockIdx.x;   // grid (16, 64) = 1024 wgs
  const int id = ((orig & 7) << 7) + (orig >> 3);       // XCD swizzle
  const int qt = id & 15, bh = id >> 4;
  const int b = bh>>4, h = bh&15;
  const int t = threadIdx.x, w = t>>6, l = t&63, lg = l>>4, ll = l&15;
  const size_t kvbase = (size_t)bh*SEQN;

  // Q fragments (B-operand), 2 sub-tiles: chunks 0,1 = Qh, 2,3 = Ql
  bf16x8 qf[2][4];
#pragma unroll
  for (int sub=0; sub<2; ++sub){
    size_t qrow = (kvbase + qt*128 + sub*64 + w*16 + ll) * 128;
#pragma unroll
    for (int i=0;i<4;i++)
      qf[sub][i] = *(const bf16x8*)(Q + qrow + i*32 + lg*8);
  }
  f32x4 o[2][4];
#pragma unroll
  for (int sub=0; sub<2; ++sub)
#pragma unroll
    for (int d=0; d<4; d++) o[sub][d] = (f32x4){0.f,0.f,0.f,0.f};
  float lsum[2] = {0.f, 0.f};

  auto stage = [&](int buf, int kv){
    int m0 = kv*64;
#pragma unroll
    for (int i=0;i<2;i++){   // K tile: [64][64] ush, 512 x 16B slots
      int s = t + i*256; int row = s>>3; int sl = s&7; int sl2 = sl ^ (row&7);
      async16(&k_lds[buf][s*8], Kh + (kvbase + m0 + row)*64 + sl2*8);
    }
#pragma unroll
    for (int i=0;i<2;i++){   // V tile: [64][64] ush, 512 x 16B slots
      int s = t + i*256; int row = s>>3; int sl = s&7; int sl2 = sl ^ (row&7);
      async16(&v_lds[buf][s*8], Vt + ((size_t)bh*64 + row)*SEQN + m0 + sl2*8);
    }
  };

  stage(0, 0);
  __syncthreads();
  const int NKV = SEQN/64;
  for (int kv=0; kv<NKV; ++kv){
    int cur = kv&1;
    if (kv+1 < NKV) stage(cur^1, kv+1);
    // scores (swapped): S^T frag = mfma(K, Q); lane: q=ll, kv=nt*16+lg*4+r
#pragma unroll
    for (int nt=0; nt<4; ++nt){
      int row = nt*16 + ll;
      bf16x8 kf0 = *(const bf16x8*)&k_lds[cur][row*64 + (((0*4+lg) ^ (row&7))*8)];
      bf16x8 kf1 = *(const bf16x8*)&k_lds[cur][row*64 + (((1*4+lg) ^ (row&7))*8)];
      f32x4 a0 = (f32x4){0.f,0.f,0.f,0.f};
      f32x4 a1 = (f32x4){0.f,0.f,0.f,0.f};
      __builtin_amdgcn_s_setprio(1);
      a0 = __builtin_amdgcn_mfma_f32_16x16x32_bf16(kf0, qf[0][0], a0, 0,0,0);
      a0 = __builtin_amdgcn_mfma_f32_16x16x32_bf16(kf1, qf[0][1], a0, 0,0,0);
      a0 = __builtin_amdgcn_mfma_f32_16x16x32_bf16(kf0, qf[0][2], a0, 0,0,0);
      a0 = __builtin_amdgcn_mfma_f32_16x16x32_bf16(kf1, qf[0][3], a0, 0,0,0);
      a1 = __builtin_amdgcn_mfma_f32_16x16x32_bf16(kf0, qf[1][0], a1, 0,0,0);
      a1 = __builtin_amdgcn_mfma_f32_16x16x32_bf16(kf1, qf[1][1], a1, 0,0,0);
      a1 = __builtin_amdgcn_mfma_f32_16x16x32_bf16(kf0, qf[1][2], a1, 0,0,0);
      a1 = __builtin_amdgcn_mfma_f32_16x16x32_bf16(kf1, qf[1][3], a1, 0,0,0);
      __builtin_amdgcn_s_setprio(0);
      int c0 = nt*8 + lg*2;
      int addr = ll*32 + (((c0>>2) ^ (ll&7))<<2) + (c0&3);
      {
        float e0 = exp2f(a0[0]), e1 = exp2f(a0[1]), e2 = exp2f(a0[2]), e3 = exp2f(a0[3]);
        lsum[0] += (e0 + e1) + (e2 + e3);
        *(uint2*)&p_lds[w][0][addr] = make_uint2(cvt_pk_bf16(e0,e1), cvt_pk_bf16(e2,e3));
      }
      {
        float e0 = exp2f(a1[0]), e1 = exp2f(a1[1]), e2 = exp2f(a1[2]), e3 = exp2f(a1[3]);
        lsum[1] += (e0 + e1) + (e2 + e3);
        *(uint2*)&p_lds[w][1][addr] = make_uint2(cvt_pk_bf16(e0,e1), cvt_pk_bf16(e2,e3));
      }
    }
    // PV: o += P @ V  (V LDS reads shared across subs in the dt loop order)
#pragma unroll
    for (int ks=0; ks<2; ++ks){
      int chunk = ks*4 + lg;
      bf16x8 pf0 = *(const bf16x8*)&p_lds[w][0][ll*32 + ((chunk ^ (ll&7))<<2)];
      bf16x8 pf1 = *(const bf16x8*)&p_lds[w][1][ll*32 + ((chunk ^ (ll&7))<<2)];
      __builtin_amdgcn_s_setprio(1);
#pragma unroll
      for (int dt=0; dt<4; ++dt){
        int row = dt*16 + ll;
        bf16x8 vf = *(const bf16x8*)&v_lds[cur][row*64 + (((ks*4+lg) ^ (row&7))*8)];
        o[0][dt] = __builtin_amdgcn_mfma_f32_16x16x32_bf16(pf0, vf, o[0][dt], 0,0,0);
        o[1][dt] = __builtin_amdgcn_mfma_f32_16x16x32_bf16(pf1, vf, o[1][dt], 0,0,0);
      }
      __builtin_amdgcn_s_setprio(0);
    }
    __syncthreads();
  }
  // epilogue per sub: softmax denom + normalized hi-only store
#pragma unroll
  for (int sub=0; sub<2; ++sub){
    float tot = lsum[sub];
    tot += __shfl_xor(tot, 16);
    tot += __shfl_xor(tot, 32);
    float inv = 1.0f / tot;
#pragma unroll
    for (int r=0;r<4;r++){
      float rl = __shfl(inv, lg*4 + r);
      int qrow = qt*128 + sub*64 + w*16 + lg*4 + r;
      size_t ob = ((size_t)(b*SEQN + qrow))*DIMC + h*64;
#pragma unroll
      for (int dt=0; dt<4; ++dt)
        att_h[ob + dt*16 + ll] = bf16_rtne(o[sub][dt][r] * rl);
    }
  }
}

// ---------------------------------------------------------------------------
extern "C" void kernel_launch(void* const* d_in, const int* in_sizes, int n_in,
                              void* d_out, int out_size, void* d_ws, size_t ws_size,
                              hipStream_t stream){
  const float* x    = (const float*)d_in[0];
  const float* Wqkv = (const float*)d_in[1];
  const float* Wout = (const float*)d_in[2];
  const float* bout = (const float*)d_in[3];
  float* out = (float*)d_out;

  char* ws = (char*)d_ws;
  size_t off = 0;
  auto walloc = [&](size_t bytes) -> void* {
    void* p = ws + off; off += (bytes + 255) & ~(size_t)255; return p;
  };
  unsigned short* x_h    = (unsigned short*)walloc((size_t)MROWS*1024*2);      // 16.8 MB
  unsigned short* wqkv_t = (unsigned short*)walloc((size_t)3072*2048*2);       // 12.6 MB
  float*          qkv    = (float*)walloc((size_t)MROWS*3072*4);               // 100.7 MB
  unsigned short* q_hl   = (unsigned short*)walloc((size_t)BH_TOT*SEQN*128*2); // 33.5 MB
  unsigned short* k_h    = (unsigned short*)walloc((size_t)BH_TOT*SEQN*64*2);  // 16.8 MB
  unsigned short* vt     = (unsigned short*)walloc((size_t)BH_TOT*64*SEQN*2);  // 16.8 MB
  unsigned short* wout_t = (unsigned short*)walloc((size_t)1024*2048*2);       // 4.2 MB
  unsigned short* att_h  = x_h;     // alias: x_h dead after QKV GEMM

  // 1) round x to bf16 hi
  round_rows_k<<<4096, 256, 0, stream>>>(x, x_h, MROWS, DIMC);
  // 2) transpose+split weights (hi|lo)
  transpose_split_k<<<dim3(3072/32, 1024/32), 256, 0, stream>>>(Wqkv, wqkv_t, 1024, 3072);
  transpose_split_k<<<dim3(1024/32, 1024/32), 256, 0, stream>>>(Wout, wout_t, 1024, 1024);
  // 3) QKV projection (2-seg split GEMM, K'=2048)
  gemm_h_k<<<dim3(64, 24), 256, 0, stream>>>(x_h, wqkv_t, qkv, nullptr, MROWS, 3072, 1024);
  // 4) extract q (scaled hi/lo), k (hi) and V^T
  split_qk_k<<<(BH_TOT*SEQN*16)/256, 256, 0, stream>>>(qkv, q_hl, k_h);
  build_vt_k<<<dim3(SEQN/64, BH_TOT), 256, 0, stream>>>(qkv, vt);
  // 5) attention: 128 q-rows/block, grid (16, 64)
  attn_k<<<dim3(16, BH_TOT), 256, 0, stream>>>(q_hl, k_h, vt, att_h);
  // 6) output projection + bias (2-seg split GEMM, K'=2048)
  gemm_h_k<<<dim3(64, 8), 256, 0, stream>>>(att_h, wout_t, out, bout, MROWS, 1024, 1024);
}